// Round 10
// baseline (8470.091 us; speedup 1.0000x reference)
//
#include <hip/hip_runtime.h>

#define NELEM     16777216   // 64^4
#define WTP_PASS  36864      // 64ci * 3 * 3 * 64co
#define NFLAG     (6 * 256 * 16)
#define EX_PAR    262144     // 256 blocks * 16 px * 64 ch (one parity slot)

__device__ float    g_bufA[NELEM];      // channel-last working buffer [px][ch]
__device__ float    g_wtp[6 * WTP_PASS];
__device__ float    g_exch[2 * EX_PAR];
__device__ unsigned g_flags[NFLAG];

static __device__ __forceinline__ float ald(const float* p) {
    return __hip_atomic_load(p, __ATOMIC_RELAXED, __HIP_MEMORY_SCOPE_AGENT);
}
static __device__ __forceinline__ void ast(float* p, float v) {
    __hip_atomic_store(p, v, __ATOMIC_RELAXED, __HIP_MEMORY_SCOPE_AGENT);
}
static __device__ __forceinline__ float g4(const float4 v, int i) {
    switch (i) { case 0: return v.x; case 1: return v.y;
                 case 2: return v.z; default: return v.w; }
}

// ring cell k -> (row,col) in the 6x6 window
static __device__ __forceinline__ void kmap(int k, int& row, int& col) {
    if      (k < 4)  { row = 0;    col = k;      }
    else if (k < 8)  { row = 5;    col = k - 4;  }
    else if (k < 12) { row = k-7;  col = 0;      }
    else if (k < 16) { row = k-11; col = 5;      }
    else if (k < 18) { row = 0;    col = k - 12; }
    else             { row = 5;    col = k - 14; }
}

// Weights: g_wtp[p][((ci*3+ky)*3+kx)*64+co] (standard order for ALL passes —
// channel-last removes the per-pass spatial transpose). Also zeroes flags.
__global__ __launch_bounds__(256) void prep(
    const float* __restrict__ w0, const float* __restrict__ w1,
    const float* __restrict__ w2, const float* __restrict__ w3,
    const float* __restrict__ w4, const float* __restrict__ w5)
{
    int gid = blockIdx.x * 256 + threadIdx.x;
    if (gid < NFLAG) g_flags[gid] = 0;
    if (gid >= 6 * WTP_PASS) return;
    int p  = gid / WTP_PASS;
    int r  = gid % WTP_PASS;
    int co = r & 63;
    int q  = r >> 6;          // ci*9 + ky*3 + kx
    int kx = q % 3;
    int t2 = q / 3;
    int ky = t2 % 3;
    int ci = t2 / 3;
    const float* src = (p==0)?w0:(p==1)?w1:(p==2)?w2:(p==3)?w3:(p==4)?w4:w5;
    g_wtp[gid] = src[co*576 + ci*9 + ky*3 + kx];
}

// x [ch][px] -> A [px][ch]  (64 x 262144 transpose, tiled via LDS)
__global__ __launch_bounds__(256) void relayout_in(
    const float* __restrict__ in, float* __restrict__ out)
{
    __shared__ float t[64][65];
    const int o = blockIdx.x;          // px tile [o*64, o*64+64)
    const int c  = threadIdx.x & 63;
    const int r4 = threadIdx.x >> 6;
#pragma unroll
    for (int r = 0; r < 16; ++r) {
        int ch = r4 * 16 + r;
        t[ch][c] = in[(size_t)ch * 262144 + o * 64 + c];
    }
    __syncthreads();
#pragma unroll
    for (int r = 0; r < 16; ++r) {
        int j = r4 * 16 + r;           // px within tile
        out[((size_t)o * 64 + j) * 64 + c] = t[c][j];
    }
}

// A [px][ch] -> out [ch][px]
__global__ __launch_bounds__(256) void relayout_out(
    const float* __restrict__ in, float* __restrict__ out)
{
    __shared__ float t[64][65];
    const int o = blockIdx.x;
    const int c  = threadIdx.x & 63;
    const int r4 = threadIdx.x >> 6;
#pragma unroll
    for (int r = 0; r < 16; ++r) {
        int j = r4 * 16 + r;           // px within tile
        t[j][c] = in[((size_t)o * 64 + j) * 64 + c];
    }
    __syncthreads();
#pragma unroll
    for (int r = 0; r < 16; ++r) {
        int ch = r4 * 16 + r;
        out[(size_t)ch * 262144 + o * 64 + c] = t[c][ch];
    }
}

// Persistent per-pass scan, channel-last. Block = 4x4 px x 64 ch; 16 waves:
// wave = (ci-group g = wv&7 [8 ci], px-half h = wv>>3 [8 px]). lane = ch.
// Weights in VGPRs; own tile in LDS (rint); 20-px halo ring via coherent
// exchange; r7-proven sync protocol (wave0 polls all 8 -> B0 -> reads).
//
// __launch_bounds__(1024) single-arg: only launchability is constrained ->
// VGPR cap 2048/16 waves = 128. Measured: (1024,2) and (1024,4) both force a
// 64-VGPR cap (2nd arg behaves as blocks/CU: N*16 waves/CU -> 8 waves/SIMD
// -> 64 regs) and spill W[8][3][3] -> 3.4 GB scratch traffic/pass. r7's
// (512,2) -> 16 waves/CU -> 128 cap, measured 120 VGPR no spill.
__global__ __launch_bounds__(1024) void pass_kernel(
    float* __restrict__ buf, const float* __restrict__ wtp,
    unsigned* __restrict__ flags, float* __restrict__ exch,
    int stp, int sup, int svp, int dir)
{
    __shared__ float lds[21504];   // 84 KB -> exactly 1 block/CU
    float* rint = lds;             // [4 row][64 ci][4 col] own tile y[prev]
    float* ring = lds + 1024;      // [64 ci][24] halo cells (k-layout)
    float* red  = lds + 2560;      // [8 g][16 px][64 lane] partials

    const int tid  = threadIdx.x;
    const int lane = tid & 63;
    const int wv   = tid >> 6;     // 0..15
    const int g    = wv & 7;       // ci-group (8 ci)
    const int h    = wv >> 3;      // px-half (px 8h..8h+7)
    const int oiB  = 2 * h;        // output rows oiB, oiB+1
    // XCD swizzle (bijective relabel; u-row neighbors share an XCD)
    const int B  = blockIdx.x;
    const int bu = ((B & 7) << 1) | ((B >> 7) & 1);
    const int bv = (B >> 3) & 15;
    const int b  = bu * 16 + bv;
    const int u0 = bu << 2, v0 = bv << 2;
    const int row = wv >> 2, col = wv & 3;    // this wave's output px = wv

    // per-lane weights for this wave's 8 ci
    float W[8][3][3];
#pragma unroll
    for (int i = 0; i < 8; ++i)
#pragma unroll
        for (int ky = 0; ky < 3; ++ky)
#pragma unroll
            for (int kx = 0; kx < 3; ++kx)
                W[i][ky][kx] = wtp[(((g*8 + i)*3 + ky)*3 + kx)*64 + lane];

    // wave 0, lanes 0..7: one spatial neighbor flag each
    int nbr = -1;
    if (lane < 8) {
        int c  = lane + (lane >= 4 ? 1 : 0);
        int nu = bu + c/3 - 1, nv = bv + c%3 - 1;
        if (nu >= 0 && nu < 16 && nv >= 0 && nv < 16) nbr = (nu*16 + nv)*16;
    }

    // staging: wave wv owns ring cell k=wv; waves 0..3 also own k=16+wv
    int kkA = -1, soA = 0, kkB = -1, soB = 0;
#pragma unroll
    for (int j = 0; j < 2; ++j) {
        int k = (j == 0) ? wv : (wv < 4 ? 16 + wv : 99);
        if (k >= 20) continue;
        int kr, kc; kmap(k, kr, kc);
        int du = (kr==0)?-1:(kr==5)?1:0, dv = (kc==0)?-1:(kc==5)?1:0;
        int nu = bu + du, nv = bv + dv;
        if (nu < 0 || nu > 15 || nv < 0 || nv > 15) continue;
        int nb = nu*16 + nv;
        int lr = (kr==0)?3:(kr==5)?0:kr-1;
        int lc = (kc==0)?3:(kc==5)?0:kc-1;
        int so = (nb*16 + lr*4 + lc)*64 + lane;
        if (j == 0) { kkA = k; soA = so; } else { kkB = k; soB = so; }
    }

    // prologue: y[t0] own px + ring cells from buf (plain, fresh at dispatch)
    const int t0 = (dir > 0) ? 0 : 63;
    rint[(row*64 + lane)*4 + col] =
        buf[((size_t)(t0*stp + (u0+row)*sup + (v0+col)*svp) << 6) + lane];
#pragma unroll
    for (int j = 0; j < 2; ++j) {
        int k = (j == 0) ? wv : (wv < 4 ? 16 + wv : 99);
        if (k >= 20) continue;
        int kr, kc; kmap(k, kr, kc);
        int gu = u0 - 1 + kr, gv = v0 - 1 + kc;
        float v = 0.f;
        if (gu >= 0 && gu < 64 && gv >= 0 && gv < 64)
            v = buf[((size_t)(t0*stp + gu*sup + gv*svp) << 6) + lane];
        ring[lane*24 + k] = v;
    }
    __syncthreads();

    for (int s = 1; s <= 63; ++s) {
        const int t = (dir > 0) ? s : 63 - s;

        // wave 0 polls all 8 neighbor flags for step s-1 (throttled)
        if (wv == 0 && s > 1) {
            const unsigned tgt = (unsigned)(s - 1);
            bool ok = (nbr < 0);
            if (!ok) ok = __hip_atomic_load(&flags[nbr], __ATOMIC_RELAXED,
                                            __HIP_MEMORY_SCOPE_AGENT) >= tgt;
            int spins = 0;
            while (!__all(ok) && spins < (1 << 22)) {
                __builtin_amdgcn_s_sleep(1);
                if (!ok) ok = __hip_atomic_load(&flags[nbr], __ATOMIC_RELAXED,
                                                __HIP_MEMORY_SCOPE_AGENT) >= tgt;
                ++spins;
            }
        }
        __syncthreads();   // B0: all neighbor halos for step s-1 published

        // x[t] prefetch (plain cached; only this thread ever writes this addr)
        const size_t oaddr =
            ((size_t)(t*stp + (u0+row)*sup + (v0+col)*svp) << 6) + lane;
        const float xv = buf[oaddr];

        // issue exchange loads now (latency overlaps PhaseA)
        float cA = 0.f, cB = 0.f;
        if (s > 1) {
            const float* xsrc = exch + (size_t)((s-1) & 1) * EX_PAR;
            if (kkA >= 0) cA = ald(xsrc + soA);
            if (kkB >= 0) cB = ald(xsrc + soB);
        }

        float acc[8];
#pragma unroll
        for (int p = 0; p < 8; ++p) acc[p] = 0.f;

        // PHASE A: own-tile taps (wr,wc in [1,4]); rows rowStart..rowStart+2
        const int rowStart = h;   // h=0 -> rint rows 0..2; h=1 -> rows 1..3
#pragma unroll
        for (int i = 0; i < 8; ++i) {
            const int ci = g*8 + i;
            const float4 R0 = *(const float4*)&rint[((rowStart+0)*64 + ci)*4];
            const float4 R1 = *(const float4*)&rint[((rowStart+1)*64 + ci)*4];
            const float4 R2 = *(const float4*)&rint[((rowStart+2)*64 + ci)*4];
#pragma unroll
            for (int lp = 0; lp < 2; ++lp) {
                const int oi = oiB + lp;
#pragma unroll
                for (int ky = 0; ky < 3; ++ky) {
                    const int wr = oi + ky;
                    if (wr < 1 || wr > 4) continue;
                    const int ri = wr - 1 - rowStart;   // 0..2
                    const float4 Rw = (ri == 0) ? R0 : (ri == 1) ? R1 : R2;
#pragma unroll
                    for (int oj = 0; oj < 4; ++oj)
#pragma unroll
                    for (int kx = 0; kx < 3; ++kx) {
                        const int wc = oj + kx;
                        if (wc < 1 || wc > 4) continue;
                        acc[lp*4+oj] = fmaf(W[i][ky][kx], g4(Rw, wc-1),
                                            acc[lp*4+oj]);
                    }
                }
            }
        }

        // land staged ring cells (exchange loads have drained under PhaseA)
        if (s > 1) {
            if (kkA >= 0) ring[lane*24 + kkA] = cA;
            if (kkB >= 0) ring[lane*24 + kkB] = cB;
        }
        __syncthreads();   // B1: ring complete

        // PHASE B: ring taps for this px-half
#pragma unroll
        for (int i = 0; i < 8; ++i) {
            const int ci = g*8 + i;
            const float4 r0a = *(const float4*)&ring[ci*24 + 0];
            const float4 r5a = *(const float4*)&ring[ci*24 + 4];
            const float4 cl  = *(const float4*)&ring[ci*24 + 8];
            const float4 cr  = *(const float4*)&ring[ci*24 + 12];
            const float2 r0b = *(const float2*)&ring[ci*24 + 16];
            const float2 r5b = *(const float2*)&ring[ci*24 + 18];
#pragma unroll
            for (int lp = 0; lp < 2; ++lp) {
                const int oi = oiB + lp;
#pragma unroll
                for (int ky = 0; ky < 3; ++ky) {
                    const int wr = oi + ky;
#pragma unroll
                    for (int oj = 0; oj < 4; ++oj)
#pragma unroll
                    for (int kx = 0; kx < 3; ++kx) {
                        const int wc = oj + kx;
                        if (wr >= 1 && wr <= 4 && wc >= 1 && wc <= 4) continue;
                        float cell;
                        if      (wr == 0) cell = (wc < 4) ? g4(r0a, wc)
                                                 : (wc == 4 ? r0b.x : r0b.y);
                        else if (wr == 5) cell = (wc < 4) ? g4(r5a, wc)
                                                 : (wc == 4 ? r5b.x : r5b.y);
                        else if (wc == 0) cell = g4(cl, wr-1);
                        else              cell = g4(cr, wr-1);
                        acc[lp*4+oj] = fmaf(W[i][ky][kx], cell, acc[lp*4+oj]);
                    }
                }
            }
        }

        // partials -> LDS: wave (g,h) wrote px 8h+lp*4+oj
#pragma unroll
        for (int p = 0; p < 8; ++p)
            red[(g*16 + 8*h + p)*64 + lane] = acc[p];
        __syncthreads();   // B2

        // wave wv reduces its own px (= wv)
        float sum = 0.f;
#pragma unroll
        for (int g2 = 0; g2 < 8; ++g2)
            sum += red[(g2*16 + wv)*64 + lane];
        const float o = xv + fmaxf(sum, 0.f);

        buf[oaddr] = o;                         // plain store (read next pass)
        if (s < 63) {
            rint[(row*64 + lane)*4 + col] = o;  // next step's own tile
            ast(exch + (size_t)(s & 1)*EX_PAR + b*1024 + wv*64 + lane, o);
        }
        __syncthreads();   // B3: drains all waves' stores before flag publish

        if (s < 63 && tid == 0)
            __hip_atomic_store(&flags[b*16], (unsigned)s, __ATOMIC_RELAXED,
                               __HIP_MEMORY_SCOPE_AGENT);
    }
}

extern "C" void kernel_launch(void* const* d_in, const int* in_sizes, int n_in,
                              void* d_out, int out_size, void* d_ws, size_t ws_size,
                              hipStream_t stream)
{
    (void)in_sizes; (void)n_in; (void)out_size; (void)d_ws; (void)ws_size;
    const float* x = (const float*)d_in[0];
    float* out = (float*)d_out;

    void *pa, *pw, *pf, *pe;
    hipGetSymbolAddress(&pa, HIP_SYMBOL(g_bufA));
    hipGetSymbolAddress(&pw, HIP_SYMBOL(g_wtp));
    hipGetSymbolAddress(&pf, HIP_SYMBOL(g_flags));
    hipGetSymbolAddress(&pe, HIP_SYMBOL(g_exch));
    float* A = (float*)pa;
    float* wtp = (float*)pw;
    unsigned* flags = (unsigned*)pf;
    float* exch = (float*)pe;

    prep<<<864, 256, 0, stream>>>(
        (const float*)d_in[1], (const float*)d_in[2], (const float*)d_in[3],
        (const float*)d_in[4], (const float*)d_in[5], (const float*)d_in[6]);

    relayout_in<<<4096, 256, 0, stream>>>(x, A);   // -> channel-last [d][h][w][ch]

    // px-unit strides: d=4096, h=64, w=1 (channel stride handled by <<6)
    // UD/DU: t=h, u=d, v=w
    pass_kernel<<<256, 1024, 0, stream>>>(A, wtp + 0*WTP_PASS, flags + 0*4096, exch, 64, 4096, 1, +1);
    pass_kernel<<<256, 1024, 0, stream>>>(A, wtp + 1*WTP_PASS, flags + 1*4096, exch, 64, 4096, 1, -1);
    // LR/RL: t=w, u=d, v=h
    pass_kernel<<<256, 1024, 0, stream>>>(A, wtp + 2*WTP_PASS, flags + 2*4096, exch, 1, 4096, 64, +1);
    pass_kernel<<<256, 1024, 0, stream>>>(A, wtp + 3*WTP_PASS, flags + 3*4096, exch, 1, 4096, 64, -1);
    // FB/BF: t=d, u=h, v=w
    pass_kernel<<<256, 1024, 0, stream>>>(A, wtp + 4*WTP_PASS, flags + 4*4096, exch, 4096, 64, 1, +1);
    pass_kernel<<<256, 1024, 0, stream>>>(A, wtp + 5*WTP_PASS, flags + 5*4096, exch, 4096, 64, 1, -1);

    relayout_out<<<4096, 256, 0, stream>>>(A, out);  // -> [ch][d][h][w]
}

// Round 12
// 3829.325 us; speedup vs baseline: 2.2119x; 2.2119x over previous
//
#include <hip/hip_runtime.h>

#define NELEM     16777216   // 64^4
#define WTP_PASS  36864      // 64ci * 3 * 3 * 64co
#define NBLK      512        // 32 x 16 tiles of 2x4 px
#define NFLAG     (6 * NBLK * 16)
#define EX_PAR    262144     // 512 blocks * 8 px * 64 ch (one parity slot)

__device__ float    g_bufA[NELEM];      // channel-last working buffer [px][ch]
__device__ float    g_wtp[6 * WTP_PASS];
__device__ float    g_exch[2 * EX_PAR];
__device__ unsigned g_flags[NFLAG];

static __device__ __forceinline__ float ald(const float* p) {
    return __hip_atomic_load(p, __ATOMIC_RELAXED, __HIP_MEMORY_SCOPE_AGENT);
}
static __device__ __forceinline__ void ast(float* p, float v) {
    __hip_atomic_store(p, v, __ATOMIC_RELAXED, __HIP_MEMORY_SCOPE_AGENT);
}
static __device__ __forceinline__ float g4(const float4 v, int i) {
    switch (i) { case 0: return v.x; case 1: return v.y;
                 case 2: return v.z; default: return v.w; }
}

// ring cell k -> (kr,kc) in the 4x6 region (interior = rows 1..2, cols 1..4)
static __device__ __forceinline__ void kmap16(int k, int& kr, int& kc) {
    if      (k < 4)   { kr = 0;     kc = k + 1; }          // top mid
    else if (k < 8)   { kr = 3;     kc = k - 3; }          // bottom mid
    else if (k < 10)  { kr = k - 7; kc = 0;     }          // left
    else if (k < 12)  { kr = k - 9; kc = 5;     }          // right
    else if (k == 12) { kr = 0;     kc = 0;     }          // corners
    else if (k == 13) { kr = 0;     kc = 5;     }
    else if (k == 14) { kr = 3;     kc = 0;     }
    else              { kr = 3;     kc = 5;     }
}

// Weights: g_wtp[p][((ci*3+ky)*3+kx)*64+co] (standard order, all passes).
// Also zeroes all sync flags.
__global__ __launch_bounds__(256) void prep(
    const float* __restrict__ w0, const float* __restrict__ w1,
    const float* __restrict__ w2, const float* __restrict__ w3,
    const float* __restrict__ w4, const float* __restrict__ w5)
{
    int gid = blockIdx.x * 256 + threadIdx.x;
    if (gid < NFLAG) g_flags[gid] = 0;
    if (gid >= 6 * WTP_PASS) return;
    int p  = gid / WTP_PASS;
    int r  = gid % WTP_PASS;
    int co = r & 63;
    int q  = r >> 6;          // ci*9 + ky*3 + kx
    int kx = q % 3;
    int t2 = q / 3;
    int ky = t2 % 3;
    int ci = t2 / 3;
    const float* src = (p==0)?w0:(p==1)?w1:(p==2)?w2:(p==3)?w3:(p==4)?w4:w5;
    g_wtp[gid] = src[co*576 + ci*9 + ky*3 + kx];
}

// x [ch][px] -> A [px][ch]
__global__ __launch_bounds__(256) void relayout_in(
    const float* __restrict__ in, float* __restrict__ out)
{
    __shared__ float t[64][65];
    const int o = blockIdx.x;
    const int c  = threadIdx.x & 63;
    const int r4 = threadIdx.x >> 6;
#pragma unroll
    for (int r = 0; r < 16; ++r) {
        int ch = r4 * 16 + r;
        t[ch][c] = in[(size_t)ch * 262144 + o * 64 + c];
    }
    __syncthreads();
#pragma unroll
    for (int r = 0; r < 16; ++r) {
        int j = r4 * 16 + r;
        out[((size_t)o * 64 + j) * 64 + c] = t[c][j];
    }
}

// A [px][ch] -> out [ch][px]
__global__ __launch_bounds__(256) void relayout_out(
    const float* __restrict__ in, float* __restrict__ out)
{
    __shared__ float t[64][65];
    const int o = blockIdx.x;
    const int c  = threadIdx.x & 63;
    const int r4 = threadIdx.x >> 6;
#pragma unroll
    for (int r = 0; r < 16; ++r) {
        int j = r4 * 16 + r;
        t[j][c] = in[((size_t)o * 64 + j) * 64 + c];
    }
    __syncthreads();
#pragma unroll
    for (int r = 0; r < 16; ++r) {
        int ch = r4 * 16 + r;
        out[(size_t)ch * 262144 + o * 64 + c] = t[c][ch];
    }
}

// Persistent per-pass scan, channel-last. 512 blocks x 512 threads;
// block = 2x4 px tile x 64 ch; 8 waves = 8 ci-groups (8 ci each, lane = ch).
// RESIDENCY BY CONSTRUCTION: amdgpu_waves_per_eu(4) forces VGPR <= 128 so
// 16 waves/CU always fit; 54 KB LDS caps blocks/CU at exactly 2; threads
// 1024 <= 2048. Hence any full 512-block launch is exactly 2 blocks/CU, all
// resident. (r11 deadlocked: (512,2) = min 2 waves/EU = 256-reg cap, body
// compiled >128 regs -> only 1 block/CU fit -> 256 blocks unplaced.)
__global__ __launch_bounds__(512)
__attribute__((amdgpu_waves_per_eu(4)))
void pass_kernel(
    float* __restrict__ buf, const float* __restrict__ wtp,
    unsigned* __restrict__ flags, float* __restrict__ exch,
    int stp, int sup, int svp, int dir)
{
    __shared__ float lds[13824];   // 54 KB -> max 2 blocks/CU by LDS
    float* rint = lds;             // [2 row][64 ci][4 col] own tile y[prev]
    float* ring = lds + 512;       // [64 ci][20] halo cells (k-layout, pad 20)
    float* red  = lds + 1792;      // [8 g][8 px][64 lane] partials

    const int tid  = threadIdx.x;
    const int lane = tid & 63;
    const int wv   = tid >> 6;     // 0..7 = ci-group g AND owned px
    // XCD swizzle: each XCD owns a contiguous 4x16 tile region
    const int B  = blockIdx.x;
    const int bu = (B & 7) * 4 + ((B >> 3) & 3);   // 0..31
    const int bv = (B >> 5) & 15;                  // 0..15
    const int b  = bu * 16 + bv;
    const int u0 = bu << 1, v0 = bv << 2;
    const int row = wv >> 2, col = wv & 3;         // owned px coords in tile

    // per-lane weights for this wave's 8 ci
    float W[8][3][3];
#pragma unroll
    for (int i = 0; i < 8; ++i)
#pragma unroll
        for (int ky = 0; ky < 3; ++ky)
#pragma unroll
            for (int kx = 0; kx < 3; ++kx)
                W[i][ky][kx] = wtp[(((wv*8 + i)*3 + ky)*3 + kx)*64 + lane];

    // wave 0, lanes 0..7: one spatial neighbor flag each (32x16 grid)
    int nbr = -1;
    if (lane < 8) {
        int c  = lane + (lane >= 4 ? 1 : 0);   // skip center of 3x3
        int nu = bu + c/3 - 1, nv = bv + c%3 - 1;
        if (nu >= 0 && nu < 32 && nv >= 0 && nv < 16) nbr = (nu*16 + nv)*16;
    }

    // staging tables: wave wv owns ring cells k=wv and k=wv+8
    int kkA = -1, soA = 0, kkB = -1, soB = 0;
#pragma unroll
    for (int j = 0; j < 2; ++j) {
        int k = wv + 8*j;
        int kr, kc; kmap16(k, kr, kc);
        int du = (kr==0)?-1:(kr==3)?1:0, dv = (kc==0)?-1:(kc==5)?1:0;
        int nu = bu + du, nv = bv + dv;
        if (nu < 0 || nu > 31 || nv < 0 || nv > 15) continue;
        int lr = (kr==0)?1:(kr==3)?0:kr-1;
        int lc = (kc==0)?3:(kc==5)?0:kc-1;
        int so = ((nu*16 + nv)*8 + lr*4 + lc)*64 + lane;
        if (j == 0) { kkA = k; soA = so; } else { kkB = k; soB = so; }
    }

    // prologue: y[t0] own px + all 16 ring cells from buf (plain, fresh)
    const int t0 = (dir > 0) ? 0 : 63;
    rint[(row*64 + lane)*4 + col] =
        buf[((size_t)(t0*stp + (u0+row)*sup + (v0+col)*svp) << 6) + lane];
#pragma unroll
    for (int j = 0; j < 2; ++j) {
        int k = wv + 8*j;
        int kr, kc; kmap16(k, kr, kc);
        int gu = u0 - 1 + kr, gv = v0 - 1 + kc;
        float v = 0.f;
        if (gu >= 0 && gu < 64 && gv >= 0 && gv < 64)
            v = buf[((size_t)(t0*stp + gu*sup + gv*svp) << 6) + lane];
        ring[lane*20 + k] = v;
    }
    __syncthreads();

    for (int s = 1; s <= 63; ++s) {
        const int t = (dir > 0) ? s : 63 - s;

        // wave 0 polls all 8 neighbor flags for step s-1 (throttled)
        if (wv == 0 && s > 1) {
            const unsigned tgt = (unsigned)(s - 1);
            bool ok = (nbr < 0);
            if (!ok) ok = __hip_atomic_load(&flags[nbr], __ATOMIC_RELAXED,
                                            __HIP_MEMORY_SCOPE_AGENT) >= tgt;
            int spins = 0;
            while (!__all(ok) && spins < (1 << 20)) {
                __builtin_amdgcn_s_sleep(1);
                if (!ok) ok = __hip_atomic_load(&flags[nbr], __ATOMIC_RELAXED,
                                                __HIP_MEMORY_SCOPE_AGENT) >= tgt;
                ++spins;
            }
        }
        __syncthreads();   // B0: all neighbor halos for step s-1 published

        // x[t] prefetch (plain cached; only this thread ever writes this addr)
        const size_t oaddr =
            ((size_t)(t*stp + (u0+row)*sup + (v0+col)*svp) << 6) + lane;
        const float xv = buf[oaddr];

        // issue exchange loads now (latency overlaps PhaseA below)
        float cA = 0.f, cB = 0.f;
        if (s > 1) {
            const float* xsrc = exch + (size_t)((s-1) & 1) * EX_PAR;
            if (kkA >= 0) cA = ald(xsrc + soA);
            if (kkB >= 0) cB = ald(xsrc + soB);
        }

        float acc[8];
#pragma unroll
        for (int p = 0; p < 8; ++p) acc[p] = 0.f;

        // PHASE A: own-tile taps (region rows 1..2, cols 1..4)
#pragma unroll
        for (int i = 0; i < 8; ++i) {
            const int ci = wv*8 + i;
            const float4 R0 = *(const float4*)&rint[(0*64 + ci)*4];
            const float4 R1 = *(const float4*)&rint[(1*64 + ci)*4];
#pragma unroll
            for (int oi = 0; oi < 2; ++oi)
#pragma unroll
            for (int ky = 0; ky < 3; ++ky) {
                const int wr = oi + ky;
                if (wr < 1 || wr > 2) continue;
                const float4 Rw = (wr == 1) ? R0 : R1;
#pragma unroll
                for (int oj = 0; oj < 4; ++oj)
#pragma unroll
                for (int kx = 0; kx < 3; ++kx) {
                    const int wc = oj + kx;
                    if (wc < 1 || wc > 4) continue;
                    acc[oi*4+oj] = fmaf(W[i][ky][kx], g4(Rw, wc-1),
                                        acc[oi*4+oj]);
                }
            }
        }

        // land staged ring cells (exchange loads drained under PhaseA)
        if (s > 1) {
            if (kkA >= 0) ring[lane*20 + kkA] = cA;
            if (kkB >= 0) ring[lane*20 + kkB] = cB;
        }
        __syncthreads();   // B1: ring complete

        // PHASE B: ring taps
#pragma unroll
        for (int i = 0; i < 8; ++i) {
            const int ci = wv*8 + i;
            const float4 top = *(const float4*)&ring[ci*20 + 0];
            const float4 bot = *(const float4*)&ring[ci*20 + 4];
            const float2 lf  = *(const float2*)&ring[ci*20 + 8];
            const float2 rt  = *(const float2*)&ring[ci*20 + 10];
            const float2 tc  = *(const float2*)&ring[ci*20 + 12];
            const float2 bc  = *(const float2*)&ring[ci*20 + 14];
#pragma unroll
            for (int oi = 0; oi < 2; ++oi)
#pragma unroll
            for (int ky = 0; ky < 3; ++ky) {
                const int wr = oi + ky;   // 0..3
#pragma unroll
                for (int oj = 0; oj < 4; ++oj)
#pragma unroll
                for (int kx = 0; kx < 3; ++kx) {
                    const int wc = oj + kx;   // 0..5
                    if (wr >= 1 && wr <= 2 && wc >= 1 && wc <= 4) continue;
                    float cell;
                    if      (wr == 0) cell = (wc == 0) ? tc.x
                                           : (wc == 5) ? tc.y : g4(top, wc-1);
                    else if (wr == 3) cell = (wc == 0) ? bc.x
                                           : (wc == 5) ? bc.y : g4(bot, wc-1);
                    else if (wc == 0) cell = (wr == 1) ? lf.x : lf.y;
                    else              cell = (wr == 1) ? rt.x : rt.y;
                    acc[oi*4+oj] = fmaf(W[i][ky][kx], cell, acc[oi*4+oj]);
                }
            }
        }

        // partials -> LDS
#pragma unroll
        for (int p = 0; p < 8; ++p)
            red[(wv*8 + p)*64 + lane] = acc[p];
        __syncthreads();   // B2

        // wave wv reduces its own px (= wv)
        float sum = 0.f;
#pragma unroll
        for (int g2 = 0; g2 < 8; ++g2)
            sum += red[(g2*8 + wv)*64 + lane];
        const float o = xv + fmaxf(sum, 0.f);

        buf[oaddr] = o;                         // plain store (read next pass)
        if (s < 63) {
            rint[(row*64 + lane)*4 + col] = o;  // next step's own tile
            ast(exch + (size_t)(s & 1)*EX_PAR + (b*8 + wv)*64 + lane, o);
        }
        __syncthreads();   // B3: drains all waves' stores before flag publish

        if (s < 63 && tid == 0)
            __hip_atomic_store(&flags[b*16], (unsigned)s, __ATOMIC_RELAXED,
                               __HIP_MEMORY_SCOPE_AGENT);
    }
}

extern "C" void kernel_launch(void* const* d_in, const int* in_sizes, int n_in,
                              void* d_out, int out_size, void* d_ws, size_t ws_size,
                              hipStream_t stream)
{
    (void)in_sizes; (void)n_in; (void)out_size; (void)d_ws; (void)ws_size;
    const float* x = (const float*)d_in[0];
    float* out = (float*)d_out;

    void *pa, *pw, *pf, *pe;
    hipGetSymbolAddress(&pa, HIP_SYMBOL(g_bufA));
    hipGetSymbolAddress(&pw, HIP_SYMBOL(g_wtp));
    hipGetSymbolAddress(&pf, HIP_SYMBOL(g_flags));
    hipGetSymbolAddress(&pe, HIP_SYMBOL(g_exch));
    float* A = (float*)pa;
    float* wtp = (float*)pw;
    unsigned* flags = (unsigned*)pf;
    float* exch = (float*)pe;

    prep<<<864, 256, 0, stream>>>(
        (const float*)d_in[1], (const float*)d_in[2], (const float*)d_in[3],
        (const float*)d_in[4], (const float*)d_in[5], (const float*)d_in[6]);

    relayout_in<<<4096, 256, 0, stream>>>(x, A);   // -> channel-last [d][h][w][ch]

    // px-unit strides: d=4096, h=64, w=1 (channel stride handled by <<6)
    // UD/DU: t=h, u=d, v=w
    pass_kernel<<<NBLK, 512, 0, stream>>>(A, wtp + 0*WTP_PASS, flags + 0*8192, exch, 64, 4096, 1, +1);
    pass_kernel<<<NBLK, 512, 0, stream>>>(A, wtp + 1*WTP_PASS, flags + 1*8192, exch, 64, 4096, 1, -1);
    // LR/RL: t=w, u=d, v=h
    pass_kernel<<<NBLK, 512, 0, stream>>>(A, wtp + 2*WTP_PASS, flags + 2*8192, exch, 1, 4096, 64, +1);
    pass_kernel<<<NBLK, 512, 0, stream>>>(A, wtp + 3*WTP_PASS, flags + 3*8192, exch, 1, 4096, 64, -1);
    // FB/BF: t=d, u=h, v=w
    pass_kernel<<<NBLK, 512, 0, stream>>>(A, wtp + 4*WTP_PASS, flags + 4*8192, exch, 4096, 64, 1, +1);
    pass_kernel<<<NBLK, 512, 0, stream>>>(A, wtp + 5*WTP_PASS, flags + 5*8192, exch, 4096, 64, 1, -1);

    relayout_out<<<4096, 256, 0, stream>>>(A, out);  // -> [ch][d][h][w]
}

// Round 13
// 3776.274 us; speedup vs baseline: 2.2430x; 1.0140x over previous
//
#include <hip/hip_runtime.h>

#define NELEM     16777216   // 64^4
#define WTP_PASS  36864      // 64ci * 3 * 3 * 64co
#define NBLK      512        // 32 x 16 tiles of 2x4 px
#define NFLAG     (6 * NBLK * 16)
#define EX_PAR    262144     // 512 blocks * 8 px * 64 ch (one parity slot)

__device__ float    g_bufA[NELEM];      // channel-last working buffer [px][ch]
__device__ float    g_wtp[6 * WTP_PASS];
__device__ float    g_exch[2 * EX_PAR];
__device__ unsigned g_flags[NFLAG];

static __device__ __forceinline__ float ald(const float* p) {
    return __hip_atomic_load(p, __ATOMIC_RELAXED, __HIP_MEMORY_SCOPE_AGENT);
}
static __device__ __forceinline__ void ast(float* p, float v) {
    __hip_atomic_store(p, v, __ATOMIC_RELAXED, __HIP_MEMORY_SCOPE_AGENT);
}
static __device__ __forceinline__ float g4(const float4 v, int i) {
    switch (i) { case 0: return v.x; case 1: return v.y;
                 case 2: return v.z; default: return v.w; }
}

// ring cell k -> (kr,kc) in the 4x6 region (interior = rows 1..2, cols 1..4)
static __device__ __forceinline__ void kmap16(int k, int& kr, int& kc) {
    if      (k < 4)   { kr = 0;     kc = k + 1; }          // top mid
    else if (k < 8)   { kr = 3;     kc = k - 3; }          // bottom mid
    else if (k < 10)  { kr = k - 7; kc = 0;     }          // left
    else if (k < 12)  { kr = k - 9; kc = 5;     }          // right
    else if (k == 12) { kr = 0;     kc = 0;     }          // corners
    else if (k == 13) { kr = 0;     kc = 5;     }
    else if (k == 14) { kr = 3;     kc = 0;     }
    else              { kr = 3;     kc = 5;     }
}

// Weights: g_wtp[p][((ci*3+ky)*3+kx)*64+co] (standard order, all passes).
// Also zeroes all sync flags.
__global__ __launch_bounds__(256) void prep(
    const float* __restrict__ w0, const float* __restrict__ w1,
    const float* __restrict__ w2, const float* __restrict__ w3,
    const float* __restrict__ w4, const float* __restrict__ w5)
{
    int gid = blockIdx.x * 256 + threadIdx.x;
    if (gid < NFLAG) g_flags[gid] = 0;
    if (gid >= 6 * WTP_PASS) return;
    int p  = gid / WTP_PASS;
    int r  = gid % WTP_PASS;
    int co = r & 63;
    int q  = r >> 6;          // ci*9 + ky*3 + kx
    int kx = q % 3;
    int t2 = q / 3;
    int ky = t2 % 3;
    int ci = t2 / 3;
    const float* src = (p==0)?w0:(p==1)?w1:(p==2)?w2:(p==3)?w3:(p==4)?w4:w5;
    g_wtp[gid] = src[co*576 + ci*9 + ky*3 + kx];
}

// x [ch][px] -> A [px][ch]
__global__ __launch_bounds__(256) void relayout_in(
    const float* __restrict__ in, float* __restrict__ out)
{
    __shared__ float t[64][65];
    const int o = blockIdx.x;
    const int c  = threadIdx.x & 63;
    const int r4 = threadIdx.x >> 6;
#pragma unroll
    for (int r = 0; r < 16; ++r) {
        int ch = r4 * 16 + r;
        t[ch][c] = in[(size_t)ch * 262144 + o * 64 + c];
    }
    __syncthreads();
#pragma unroll
    for (int r = 0; r < 16; ++r) {
        int j = r4 * 16 + r;
        out[((size_t)o * 64 + j) * 64 + c] = t[c][j];
    }
}

// A [px][ch] -> out [ch][px]
__global__ __launch_bounds__(256) void relayout_out(
    const float* __restrict__ in, float* __restrict__ out)
{
    __shared__ float t[64][65];
    const int o = blockIdx.x;
    const int c  = threadIdx.x & 63;
    const int r4 = threadIdx.x >> 6;
#pragma unroll
    for (int r = 0; r < 16; ++r) {
        int j = r4 * 16 + r;
        t[j][c] = in[((size_t)o * 64 + j) * 64 + c];
    }
    __syncthreads();
#pragma unroll
    for (int r = 0; r < 16; ++r) {
        int ch = r4 * 16 + r;
        out[(size_t)ch * 262144 + o * 64 + c] = t[c][ch];
    }
}

// Persistent per-pass scan, channel-last. 512 blocks x 512 threads;
// block = 2x4 px tile x 64 ch; 8 waves = 8 ci-groups (8 ci each, lane = ch).
//
// Occupancy control (hard-won empirics on this compiler):
//   (1024,*), (1024): allocator targets 8 waves/EU -> 64-reg budget -> spills
//       W[8][3][3] -> 3.4 GB scratch traffic/pass. 1024-thread blocks banned.
//   (512,2): budget 256; allocator landed at 120 (r7, OK) but >128 for the
//       near-identical r11 body -> only 1 block/CU resident -> deadlock.
//   waves_per_eu(4) min-only (r12): max unbounded -> allocator still chose
//       64-reg/8-wave target -> spill again (1.48 GB/pass).
// Fix: waves_per_eu(4,4) clamps BOTH sides -> budget = exactly 128, no
// incentive to shrink to 64. 16 waves/CU guaranteed; 54 KB LDS caps blocks/CU
// at 2 -> any full 512-block launch is exactly 2 blocks/CU, all resident.
__global__ __launch_bounds__(512)
__attribute__((amdgpu_waves_per_eu(4, 4)))
void pass_kernel(
    float* __restrict__ buf, const float* __restrict__ wtp,
    unsigned* __restrict__ flags, float* __restrict__ exch,
    int stp, int sup, int svp, int dir)
{
    __shared__ float lds[13824];   // 54 KB -> max 2 blocks/CU by LDS
    float* rint = lds;             // [2 row][64 ci][4 col] own tile y[prev]
    float* ring = lds + 512;       // [64 ci][20] halo cells (k-layout, pad 20)
    float* red  = lds + 1792;      // [8 g][8 px][64 lane] partials

    const int tid  = threadIdx.x;
    const int lane = tid & 63;
    const int wv   = tid >> 6;     // 0..7 = ci-group g AND owned px
    // XCD swizzle: each XCD owns a contiguous 4x16 tile region
    const int B  = blockIdx.x;
    const int bu = (B & 7) * 4 + ((B >> 3) & 3);   // 0..31
    const int bv = (B >> 5) & 15;                  // 0..15
    const int b  = bu * 16 + bv;
    const int u0 = bu << 1, v0 = bv << 2;
    const int row = wv >> 2, col = wv & 3;         // owned px coords in tile

    // per-lane weights for this wave's 8 ci
    float W[8][3][3];
#pragma unroll
    for (int i = 0; i < 8; ++i)
#pragma unroll
        for (int ky = 0; ky < 3; ++ky)
#pragma unroll
            for (int kx = 0; kx < 3; ++kx)
                W[i][ky][kx] = wtp[(((wv*8 + i)*3 + ky)*3 + kx)*64 + lane];

    // wave 0, lanes 0..7: one spatial neighbor flag each (32x16 grid)
    int nbr = -1;
    if (lane < 8) {
        int c  = lane + (lane >= 4 ? 1 : 0);   // skip center of 3x3
        int nu = bu + c/3 - 1, nv = bv + c%3 - 1;
        if (nu >= 0 && nu < 32 && nv >= 0 && nv < 16) nbr = (nu*16 + nv)*16;
    }

    // staging tables: wave wv owns ring cells k=wv and k=wv+8
    int kkA = -1, soA = 0, kkB = -1, soB = 0;
#pragma unroll
    for (int j = 0; j < 2; ++j) {
        int k = wv + 8*j;
        int kr, kc; kmap16(k, kr, kc);
        int du = (kr==0)?-1:(kr==3)?1:0, dv = (kc==0)?-1:(kc==5)?1:0;
        int nu = bu + du, nv = bv + dv;
        if (nu < 0 || nu > 31 || nv < 0 || nv > 15) continue;
        int lr = (kr==0)?1:(kr==3)?0:kr-1;
        int lc = (kc==0)?3:(kc==5)?0:kc-1;
        int so = ((nu*16 + nv)*8 + lr*4 + lc)*64 + lane;
        if (j == 0) { kkA = k; soA = so; } else { kkB = k; soB = so; }
    }

    // prologue: y[t0] own px + all 16 ring cells from buf (plain, fresh)
    const int t0 = (dir > 0) ? 0 : 63;
    rint[(row*64 + lane)*4 + col] =
        buf[((size_t)(t0*stp + (u0+row)*sup + (v0+col)*svp) << 6) + lane];
#pragma unroll
    for (int j = 0; j < 2; ++j) {
        int k = wv + 8*j;
        int kr, kc; kmap16(k, kr, kc);
        int gu = u0 - 1 + kr, gv = v0 - 1 + kc;
        float v = 0.f;
        if (gu >= 0 && gu < 64 && gv >= 0 && gv < 64)
            v = buf[((size_t)(t0*stp + gu*sup + gv*svp) << 6) + lane];
        ring[lane*20 + k] = v;
    }
    __syncthreads();

    for (int s = 1; s <= 63; ++s) {
        const int t = (dir > 0) ? s : 63 - s;

        // wave 0 polls all 8 neighbor flags for step s-1 (throttled)
        if (wv == 0 && s > 1) {
            const unsigned tgt = (unsigned)(s - 1);
            bool ok = (nbr < 0);
            if (!ok) ok = __hip_atomic_load(&flags[nbr], __ATOMIC_RELAXED,
                                            __HIP_MEMORY_SCOPE_AGENT) >= tgt;
            int spins = 0;
            while (!__all(ok) && spins < (1 << 20)) {
                __builtin_amdgcn_s_sleep(1);
                if (!ok) ok = __hip_atomic_load(&flags[nbr], __ATOMIC_RELAXED,
                                                __HIP_MEMORY_SCOPE_AGENT) >= tgt;
                ++spins;
            }
        }
        __syncthreads();   // B0: all neighbor halos for step s-1 published

        // x[t] prefetch (plain cached; only this thread ever writes this addr)
        const size_t oaddr =
            ((size_t)(t*stp + (u0+row)*sup + (v0+col)*svp) << 6) + lane;
        const float xv = buf[oaddr];

        // issue exchange loads now (latency overlaps PhaseA below)
        float cA = 0.f, cB = 0.f;
        if (s > 1) {
            const float* xsrc = exch + (size_t)((s-1) & 1) * EX_PAR;
            if (kkA >= 0) cA = ald(xsrc + soA);
            if (kkB >= 0) cB = ald(xsrc + soB);
        }

        float acc[8];
#pragma unroll
        for (int p = 0; p < 8; ++p) acc[p] = 0.f;

        // PHASE A: own-tile taps (region rows 1..2, cols 1..4)
#pragma unroll
        for (int i = 0; i < 8; ++i) {
            const int ci = wv*8 + i;
            const float4 R0 = *(const float4*)&rint[(0*64 + ci)*4];
            const float4 R1 = *(const float4*)&rint[(1*64 + ci)*4];
#pragma unroll
            for (int oi = 0; oi < 2; ++oi)
#pragma unroll
            for (int ky = 0; ky < 3; ++ky) {
                const int wr = oi + ky;
                if (wr < 1 || wr > 2) continue;
                const float4 Rw = (wr == 1) ? R0 : R1;
#pragma unroll
                for (int oj = 0; oj < 4; ++oj)
#pragma unroll
                for (int kx = 0; kx < 3; ++kx) {
                    const int wc = oj + kx;
                    if (wc < 1 || wc > 4) continue;
                    acc[oi*4+oj] = fmaf(W[i][ky][kx], g4(Rw, wc-1),
                                        acc[oi*4+oj]);
                }
            }
        }

        // land staged ring cells (exchange loads drained under PhaseA)
        if (s > 1) {
            if (kkA >= 0) ring[lane*20 + kkA] = cA;
            if (kkB >= 0) ring[lane*20 + kkB] = cB;
        }
        __syncthreads();   // B1: ring complete

        // PHASE B: ring taps
#pragma unroll
        for (int i = 0; i < 8; ++i) {
            const int ci = wv*8 + i;
            const float4 top = *(const float4*)&ring[ci*20 + 0];
            const float4 bot = *(const float4*)&ring[ci*20 + 4];
            const float2 lf  = *(const float2*)&ring[ci*20 + 8];
            const float2 rt  = *(const float2*)&ring[ci*20 + 10];
            const float2 tc  = *(const float2*)&ring[ci*20 + 12];
            const float2 bc  = *(const float2*)&ring[ci*20 + 14];
#pragma unroll
            for (int oi = 0; oi < 2; ++oi)
#pragma unroll
            for (int ky = 0; ky < 3; ++ky) {
                const int wr = oi + ky;   // 0..3
#pragma unroll
                for (int oj = 0; oj < 4; ++oj)
#pragma unroll
                for (int kx = 0; kx < 3; ++kx) {
                    const int wc = oj + kx;   // 0..5
                    if (wr >= 1 && wr <= 2 && wc >= 1 && wc <= 4) continue;
                    float cell;
                    if      (wr == 0) cell = (wc == 0) ? tc.x
                                           : (wc == 5) ? tc.y : g4(top, wc-1);
                    else if (wr == 3) cell = (wc == 0) ? bc.x
                                           : (wc == 5) ? bc.y : g4(bot, wc-1);
                    else if (wc == 0) cell = (wr == 1) ? lf.x : lf.y;
                    else              cell = (wr == 1) ? rt.x : rt.y;
                    acc[oi*4+oj] = fmaf(W[i][ky][kx], cell, acc[oi*4+oj]);
                }
            }
        }

        // partials -> LDS
#pragma unroll
        for (int p = 0; p < 8; ++p)
            red[(wv*8 + p)*64 + lane] = acc[p];
        __syncthreads();   // B2

        // wave wv reduces its own px (= wv)
        float sum = 0.f;
#pragma unroll
        for (int g2 = 0; g2 < 8; ++g2)
            sum += red[(g2*8 + wv)*64 + lane];
        const float o = xv + fmaxf(sum, 0.f);

        buf[oaddr] = o;                         // plain store (read next pass)
        if (s < 63) {
            rint[(row*64 + lane)*4 + col] = o;  // next step's own tile
            ast(exch + (size_t)(s & 1)*EX_PAR + (b*8 + wv)*64 + lane, o);
        }
        __syncthreads();   // B3: drains all waves' stores before flag publish

        if (s < 63 && tid == 0)
            __hip_atomic_store(&flags[b*16], (unsigned)s, __ATOMIC_RELAXED,
                               __HIP_MEMORY_SCOPE_AGENT);
    }
}

extern "C" void kernel_launch(void* const* d_in, const int* in_sizes, int n_in,
                              void* d_out, int out_size, void* d_ws, size_t ws_size,
                              hipStream_t stream)
{
    (void)in_sizes; (void)n_in; (void)out_size; (void)d_ws; (void)ws_size;
    const float* x = (const float*)d_in[0];
    float* out = (float*)d_out;

    void *pa, *pw, *pf, *pe;
    hipGetSymbolAddress(&pa, HIP_SYMBOL(g_bufA));
    hipGetSymbolAddress(&pw, HIP_SYMBOL(g_wtp));
    hipGetSymbolAddress(&pf, HIP_SYMBOL(g_flags));
    hipGetSymbolAddress(&pe, HIP_SYMBOL(g_exch));
    float* A = (float*)pa;
    float* wtp = (float*)pw;
    unsigned* flags = (unsigned*)pf;
    float* exch = (float*)pe;

    prep<<<864, 256, 0, stream>>>(
        (const float*)d_in[1], (const float*)d_in[2], (const float*)d_in[3],
        (const float*)d_in[4], (const float*)d_in[5], (const float*)d_in[6]);

    relayout_in<<<4096, 256, 0, stream>>>(x, A);   // -> channel-last [d][h][w][ch]

    // px-unit strides: d=4096, h=64, w=1 (channel stride handled by <<6)
    // UD/DU: t=h, u=d, v=w
    pass_kernel<<<NBLK, 512, 0, stream>>>(A, wtp + 0*WTP_PASS, flags + 0*8192, exch, 64, 4096, 1, +1);
    pass_kernel<<<NBLK, 512, 0, stream>>>(A, wtp + 1*WTP_PASS, flags + 1*8192, exch, 64, 4096, 1, -1);
    // LR/RL: t=w, u=d, v=h
    pass_kernel<<<NBLK, 512, 0, stream>>>(A, wtp + 2*WTP_PASS, flags + 2*8192, exch, 1, 4096, 64, +1);
    pass_kernel<<<NBLK, 512, 0, stream>>>(A, wtp + 3*WTP_PASS, flags + 3*8192, exch, 1, 4096, 64, -1);
    // FB/BF: t=d, u=h, v=w
    pass_kernel<<<NBLK, 512, 0, stream>>>(A, wtp + 4*WTP_PASS, flags + 4*8192, exch, 4096, 64, 1, +1);
    pass_kernel<<<NBLK, 512, 0, stream>>>(A, wtp + 5*WTP_PASS, flags + 5*8192, exch, 4096, 64, 1, -1);

    relayout_out<<<4096, 256, 0, stream>>>(A, out);  // -> [ch][d][h][w]
}

// Round 14
// 3767.745 us; speedup vs baseline: 2.2481x; 1.0023x over previous
//
#include <hip/hip_runtime.h>

#define NELEM     16777216   // 64^4
#define WTP_PASS  36864      // 64ci * 3 * 3 * 64co
#define NBLK      512        // 32 x 16 tiles of 2x4 px
#define NFLAG     (6 * NBLK * 16)
#define EX_PAR    262144     // 512 blocks * 8 px * 64 ch (one parity slot)

__device__ float    g_bufA[NELEM];      // channel-last working buffer [px][ch]
__device__ float    g_wtp[6 * WTP_PASS];
__device__ float    g_exch[2 * EX_PAR];
__device__ unsigned g_flags[NFLAG];

static __device__ __forceinline__ float ald(const float* p) {
    return __hip_atomic_load(p, __ATOMIC_RELAXED, __HIP_MEMORY_SCOPE_AGENT);
}
static __device__ __forceinline__ void ast(float* p, float v) {
    __hip_atomic_store(p, v, __ATOMIC_RELAXED, __HIP_MEMORY_SCOPE_AGENT);
}
static __device__ __forceinline__ float g4(const float4 v, int i) {
    switch (i) { case 0: return v.x; case 1: return v.y;
                 case 2: return v.z; default: return v.w; }
}

// ring cell k -> (kr,kc) in the 4x6 region (interior = rows 1..2, cols 1..4)
static __device__ __forceinline__ void kmap16(int k, int& kr, int& kc) {
    if      (k < 4)   { kr = 0;     kc = k + 1; }          // top mid
    else if (k < 8)   { kr = 3;     kc = k - 3; }          // bottom mid
    else if (k < 10)  { kr = k - 7; kc = 0;     }          // left
    else if (k < 12)  { kr = k - 9; kc = 5;     }          // right
    else if (k == 12) { kr = 0;     kc = 0;     }          // corners
    else if (k == 13) { kr = 0;     kc = 5;     }
    else if (k == 14) { kr = 3;     kc = 0;     }
    else              { kr = 3;     kc = 5;     }
}

// Weights: g_wtp[p][((ci*3+ky)*3+kx)*64+co] (standard order, all passes).
// Also zeroes all sync flags.
__global__ __launch_bounds__(256) void prep(
    const float* __restrict__ w0, const float* __restrict__ w1,
    const float* __restrict__ w2, const float* __restrict__ w3,
    const float* __restrict__ w4, const float* __restrict__ w5)
{
    int gid = blockIdx.x * 256 + threadIdx.x;
    if (gid < NFLAG) g_flags[gid] = 0;
    if (gid >= 6 * WTP_PASS) return;
    int p  = gid / WTP_PASS;
    int r  = gid % WTP_PASS;
    int co = r & 63;
    int q  = r >> 6;          // ci*9 + ky*3 + kx
    int kx = q % 3;
    int t2 = q / 3;
    int ky = t2 % 3;
    int ci = t2 / 3;
    const float* src = (p==0)?w0:(p==1)?w1:(p==2)?w2:(p==3)?w3:(p==4)?w4:w5;
    g_wtp[gid] = src[co*576 + ci*9 + ky*3 + kx];
}

// x [ch][px] -> A [px][ch]
__global__ __launch_bounds__(256) void relayout_in(
    const float* __restrict__ in, float* __restrict__ out)
{
    __shared__ float t[64][65];
    const int o = blockIdx.x;
    const int c  = threadIdx.x & 63;
    const int r4 = threadIdx.x >> 6;
#pragma unroll
    for (int r = 0; r < 16; ++r) {
        int ch = r4 * 16 + r;
        t[ch][c] = in[(size_t)ch * 262144 + o * 64 + c];
    }
    __syncthreads();
#pragma unroll
    for (int r = 0; r < 16; ++r) {
        int j = r4 * 16 + r;
        out[((size_t)o * 64 + j) * 64 + c] = t[c][j];
    }
}

// A [px][ch] -> out [ch][px]
__global__ __launch_bounds__(256) void relayout_out(
    const float* __restrict__ in, float* __restrict__ out)
{
    __shared__ float t[64][65];
    const int o = blockIdx.x;
    const int c  = threadIdx.x & 63;
    const int r4 = threadIdx.x >> 6;
#pragma unroll
    for (int r = 0; r < 16; ++r) {
        int j = r4 * 16 + r;
        t[j][c] = in[((size_t)o * 64 + j) * 64 + c];
    }
    __syncthreads();
#pragma unroll
    for (int r = 0; r < 16; ++r) {
        int ch = r4 * 16 + r;
        out[(size_t)ch * 262144 + o * 64 + c] = t[c][ch];
    }
}

// Persistent per-pass scan, channel-last. 512 blocks x 512 threads;
// block = 2x4 px tile x 64 ch; 8 waves = 8 ci-groups (8 ci each, lane = ch).
//
// Register/occupancy control — empirical law for this toolchain (7 configs):
//   ONLY the 2nd __launch_bounds__ arg is honored (min waves/EU -> VGPR
//   budget = 512-reg file / waves). (512,2) -> budget 256 (r7: 120 regs OK;
//   r11: >128 -> 1 block/CU -> deadlock). Single-arg / amdgpu_waves_per_eu
//   attribute forms -> default 8-wave target -> 64-reg budget -> W[8][3][3]
//   spills -> 1.5-3.4 GB scratch traffic. 1024-thread blocks always 64.
// Fix: (512, 4) -> budget exactly 128. Body needs ~112 -> no spill, and
// <=128 regs guarantees 4 waves/EU -> 2 blocks/CU residency by construction
// (54 KB LDS caps at 2; 512 blocks = 256 CU x 2, all resident).
__global__ __launch_bounds__(512, 4)
void pass_kernel(
    float* __restrict__ buf, const float* __restrict__ wtp,
    unsigned* __restrict__ flags, float* __restrict__ exch,
    int stp, int sup, int svp, int dir)
{
    __shared__ float lds[13824];   // 54 KB -> max 2 blocks/CU by LDS
    float* rint = lds;             // [2 row][64 ci][4 col] own tile y[prev]
    float* ring = lds + 512;       // [64 ci][20] halo cells (k-layout, pad 20)
    float* red  = lds + 1792;      // [8 g][8 px][64 lane] partials

    const int tid  = threadIdx.x;
    const int lane = tid & 63;
    const int wv   = tid >> 6;     // 0..7 = ci-group g AND owned px
    // XCD swizzle: each XCD owns a contiguous 4x16 tile region
    const int B  = blockIdx.x;
    const int bu = (B & 7) * 4 + ((B >> 3) & 3);   // 0..31
    const int bv = (B >> 5) & 15;                  // 0..15
    const int b  = bu * 16 + bv;
    const int u0 = bu << 1, v0 = bv << 2;
    const int row = wv >> 2, col = wv & 3;         // owned px coords in tile

    // per-lane weights for this wave's 8 ci
    float W[8][3][3];
#pragma unroll
    for (int i = 0; i < 8; ++i)
#pragma unroll
        for (int ky = 0; ky < 3; ++ky)
#pragma unroll
            for (int kx = 0; kx < 3; ++kx)
                W[i][ky][kx] = wtp[(((wv*8 + i)*3 + ky)*3 + kx)*64 + lane];

    // wave 0, lanes 0..7: one spatial neighbor flag each (32x16 grid)
    int nbr = -1;
    if (lane < 8) {
        int c  = lane + (lane >= 4 ? 1 : 0);   // skip center of 3x3
        int nu = bu + c/3 - 1, nv = bv + c%3 - 1;
        if (nu >= 0 && nu < 32 && nv >= 0 && nv < 16) nbr = (nu*16 + nv)*16;
    }

    // staging tables: wave wv owns ring cells k=wv and k=wv+8
    int kkA = -1, soA = 0, kkB = -1, soB = 0;
#pragma unroll
    for (int j = 0; j < 2; ++j) {
        int k = wv + 8*j;
        int kr, kc; kmap16(k, kr, kc);
        int du = (kr==0)?-1:(kr==3)?1:0, dv = (kc==0)?-1:(kc==5)?1:0;
        int nu = bu + du, nv = bv + dv;
        if (nu < 0 || nu > 31 || nv < 0 || nv > 15) continue;
        int lr = (kr==0)?1:(kr==3)?0:kr-1;
        int lc = (kc==0)?3:(kc==5)?0:kc-1;
        int so = ((nu*16 + nv)*8 + lr*4 + lc)*64 + lane;
        if (j == 0) { kkA = k; soA = so; } else { kkB = k; soB = so; }
    }

    // prologue: y[t0] own px + all 16 ring cells from buf (plain, fresh)
    const int t0 = (dir > 0) ? 0 : 63;
    rint[(row*64 + lane)*4 + col] =
        buf[((size_t)(t0*stp + (u0+row)*sup + (v0+col)*svp) << 6) + lane];
#pragma unroll
    for (int j = 0; j < 2; ++j) {
        int k = wv + 8*j;
        int kr, kc; kmap16(k, kr, kc);
        int gu = u0 - 1 + kr, gv = v0 - 1 + kc;
        float v = 0.f;
        if (gu >= 0 && gu < 64 && gv >= 0 && gv < 64)
            v = buf[((size_t)(t0*stp + gu*sup + gv*svp) << 6) + lane];
        ring[lane*20 + k] = v;
    }
    __syncthreads();

    for (int s = 1; s <= 63; ++s) {
        const int t = (dir > 0) ? s : 63 - s;

        // wave 0 polls all 8 neighbor flags for step s-1 (throttled)
        if (wv == 0 && s > 1) {
            const unsigned tgt = (unsigned)(s - 1);
            bool ok = (nbr < 0);
            if (!ok) ok = __hip_atomic_load(&flags[nbr], __ATOMIC_RELAXED,
                                            __HIP_MEMORY_SCOPE_AGENT) >= tgt;
            int spins = 0;
            while (!__all(ok) && spins < (1 << 20)) {
                __builtin_amdgcn_s_sleep(1);
                if (!ok) ok = __hip_atomic_load(&flags[nbr], __ATOMIC_RELAXED,
                                                __HIP_MEMORY_SCOPE_AGENT) >= tgt;
                ++spins;
            }
        }
        __syncthreads();   // B0: all neighbor halos for step s-1 published

        // x[t] prefetch (plain cached; only this thread ever writes this addr)
        const size_t oaddr =
            ((size_t)(t*stp + (u0+row)*sup + (v0+col)*svp) << 6) + lane;
        const float xv = buf[oaddr];

        // issue exchange loads now (latency overlaps PhaseA below)
        float cA = 0.f, cB = 0.f;
        if (s > 1) {
            const float* xsrc = exch + (size_t)((s-1) & 1) * EX_PAR;
            if (kkA >= 0) cA = ald(xsrc + soA);
            if (kkB >= 0) cB = ald(xsrc + soB);
        }

        float acc[8];
#pragma unroll
        for (int p = 0; p < 8; ++p) acc[p] = 0.f;

        // PHASE A: own-tile taps (region rows 1..2, cols 1..4)
#pragma unroll
        for (int i = 0; i < 8; ++i) {
            const int ci = wv*8 + i;
            const float4 R0 = *(const float4*)&rint[(0*64 + ci)*4];
            const float4 R1 = *(const float4*)&rint[(1*64 + ci)*4];
#pragma unroll
            for (int oi = 0; oi < 2; ++oi)
#pragma unroll
            for (int ky = 0; ky < 3; ++ky) {
                const int wr = oi + ky;
                if (wr < 1 || wr > 2) continue;
                const float4 Rw = (wr == 1) ? R0 : R1;
#pragma unroll
                for (int oj = 0; oj < 4; ++oj)
#pragma unroll
                for (int kx = 0; kx < 3; ++kx) {
                    const int wc = oj + kx;
                    if (wc < 1 || wc > 4) continue;
                    acc[oi*4+oj] = fmaf(W[i][ky][kx], g4(Rw, wc-1),
                                        acc[oi*4+oj]);
                }
            }
        }

        // land staged ring cells (exchange loads drained under PhaseA)
        if (s > 1) {
            if (kkA >= 0) ring[lane*20 + kkA] = cA;
            if (kkB >= 0) ring[lane*20 + kkB] = cB;
        }
        __syncthreads();   // B1: ring complete

        // PHASE B: ring taps
#pragma unroll
        for (int i = 0; i < 8; ++i) {
            const int ci = wv*8 + i;
            const float4 top = *(const float4*)&ring[ci*20 + 0];
            const float4 bot = *(const float4*)&ring[ci*20 + 4];
            const float2 lf  = *(const float2*)&ring[ci*20 + 8];
            const float2 rt  = *(const float2*)&ring[ci*20 + 10];
            const float2 tc  = *(const float2*)&ring[ci*20 + 12];
            const float2 bc  = *(const float2*)&ring[ci*20 + 14];
#pragma unroll
            for (int oi = 0; oi < 2; ++oi)
#pragma unroll
            for (int ky = 0; ky < 3; ++ky) {
                const int wr = oi + ky;   // 0..3
#pragma unroll
                for (int oj = 0; oj < 4; ++oj)
#pragma unroll
                for (int kx = 0; kx < 3; ++kx) {
                    const int wc = oj + kx;   // 0..5
                    if (wr >= 1 && wr <= 2 && wc >= 1 && wc <= 4) continue;
                    float cell;
                    if      (wr == 0) cell = (wc == 0) ? tc.x
                                           : (wc == 5) ? tc.y : g4(top, wc-1);
                    else if (wr == 3) cell = (wc == 0) ? bc.x
                                           : (wc == 5) ? bc.y : g4(bot, wc-1);
                    else if (wc == 0) cell = (wr == 1) ? lf.x : lf.y;
                    else              cell = (wr == 1) ? rt.x : rt.y;
                    acc[oi*4+oj] = fmaf(W[i][ky][kx], cell, acc[oi*4+oj]);
                }
            }
        }

        // partials -> LDS
#pragma unroll
        for (int p = 0; p < 8; ++p)
            red[(wv*8 + p)*64 + lane] = acc[p];
        __syncthreads();   // B2

        // wave wv reduces its own px (= wv)
        float sum = 0.f;
#pragma unroll
        for (int g2 = 0; g2 < 8; ++g2)
            sum += red[(g2*8 + wv)*64 + lane];
        const float o = xv + fmaxf(sum, 0.f);

        buf[oaddr] = o;                         // plain store (read next pass)
        if (s < 63) {
            rint[(row*64 + lane)*4 + col] = o;  // next step's own tile
            ast(exch + (size_t)(s & 1)*EX_PAR + (b*8 + wv)*64 + lane, o);
        }
        __syncthreads();   // B3: drains all waves' stores before flag publish

        if (s < 63 && tid == 0)
            __hip_atomic_store(&flags[b*16], (unsigned)s, __ATOMIC_RELAXED,
                               __HIP_MEMORY_SCOPE_AGENT);
    }
}

extern "C" void kernel_launch(void* const* d_in, const int* in_sizes, int n_in,
                              void* d_out, int out_size, void* d_ws, size_t ws_size,
                              hipStream_t stream)
{
    (void)in_sizes; (void)n_in; (void)out_size; (void)d_ws; (void)ws_size;
    const float* x = (const float*)d_in[0];
    float* out = (float*)d_out;

    void *pa, *pw, *pf, *pe;
    hipGetSymbolAddress(&pa, HIP_SYMBOL(g_bufA));
    hipGetSymbolAddress(&pw, HIP_SYMBOL(g_wtp));
    hipGetSymbolAddress(&pf, HIP_SYMBOL(g_flags));
    hipGetSymbolAddress(&pe, HIP_SYMBOL(g_exch));
    float* A = (float*)pa;
    float* wtp = (float*)pw;
    unsigned* flags = (unsigned*)pf;
    float* exch = (float*)pe;

    prep<<<864, 256, 0, stream>>>(
        (const float*)d_in[1], (const float*)d_in[2], (const float*)d_in[3],
        (const float*)d_in[4], (const float*)d_in[5], (const float*)d_in[6]);

    relayout_in<<<4096, 256, 0, stream>>>(x, A);   // -> channel-last [d][h][w][ch]

    // px-unit strides: d=4096, h=64, w=1 (channel stride handled by <<6)
    // UD/DU: t=h, u=d, v=w
    pass_kernel<<<NBLK, 512, 0, stream>>>(A, wtp + 0*WTP_PASS, flags + 0*8192, exch, 64, 4096, 1, +1);
    pass_kernel<<<NBLK, 512, 0, stream>>>(A, wtp + 1*WTP_PASS, flags + 1*8192, exch, 64, 4096, 1, -1);
    // LR/RL: t=w, u=d, v=h
    pass_kernel<<<NBLK, 512, 0, stream>>>(A, wtp + 2*WTP_PASS, flags + 2*8192, exch, 1, 4096, 64, +1);
    pass_kernel<<<NBLK, 512, 0, stream>>>(A, wtp + 3*WTP_PASS, flags + 3*8192, exch, 1, 4096, 64, -1);
    // FB/BF: t=d, u=h, v=w
    pass_kernel<<<NBLK, 512, 0, stream>>>(A, wtp + 4*WTP_PASS, flags + 4*8192, exch, 4096, 64, 1, +1);
    pass_kernel<<<NBLK, 512, 0, stream>>>(A, wtp + 5*WTP_PASS, flags + 5*8192, exch, 4096, 64, 1, -1);

    relayout_out<<<4096, 256, 0, stream>>>(A, out);  // -> [ch][d][h][w]
}

// Round 15
// 2495.695 us; speedup vs baseline: 3.3939x; 1.5097x over previous
//
#include <hip/hip_runtime.h>

#define NELEM     16777216   // 64^4
#define CI_STRIDE 262144     // 64^3
#define WTP_PASS  36864      // 64ci * 3 * 3 * 64co
#define NFLAG     (6 * 256 * 16)
#define EX_PAR    262144     // 256 blocks * 16 px * 64 ch (one parity slot)

__device__ float    g_bufA[NELEM + 32];
__device__ float    g_bufB[NELEM + 32];
__device__ float    g_wtp[6 * WTP_PASS];
__device__ float    g_exch[2 * EX_PAR];
__device__ unsigned g_flags[NFLAG];

static __device__ __forceinline__ float ald(const float* p) {
    return __hip_atomic_load(p, __ATOMIC_RELAXED, __HIP_MEMORY_SCOPE_AGENT);
}
static __device__ __forceinline__ void ast(float* p, float v) {
    __hip_atomic_store(p, v, __ATOMIC_RELAXED, __HIP_MEMORY_SCOPE_AGENT);
}
static __device__ __forceinline__ float g4(const float4 v, int i) {
    switch (i) { case 0: return v.x; case 1: return v.y;
                 case 2: return v.z; default: return v.w; }
}

// ring cell k -> (row,col) in the 6x6 window
static __device__ __forceinline__ void kmap(int k, int& row, int& col) {
    if      (k < 4)  { row = 0;    col = k;      }
    else if (k < 8)  { row = 5;    col = k - 4;  }
    else if (k < 12) { row = k-7;  col = 0;      }
    else if (k < 16) { row = k-11; col = 5;      }
    else if (k < 18) { row = 0;    col = k - 12; }
    else             { row = 5;    col = k - 14; }
}

__global__ __launch_bounds__(256) void prep(
    const float* __restrict__ w0, const float* __restrict__ w1,
    const float* __restrict__ w2, const float* __restrict__ w3,
    const float* __restrict__ w4, const float* __restrict__ w5)
{
    int gid = blockIdx.x * 256 + threadIdx.x;
    if (gid < NFLAG) g_flags[gid] = 0;
    if (gid >= 6 * WTP_PASS) return;
    int p  = gid / WTP_PASS;
    int r  = gid % WTP_PASS;
    int co = r & 63;
    int q  = r >> 6;          // ci*9 + ky*3 + kx
    int kx = q % 3;
    int t2 = q / 3;
    int ky = t2 % 3;
    int ci = t2 / 3;
    const float* src = (p==0)?w0:(p==1)?w1:(p==2)?w2:(p==3)?w3:(p==4)?w4:w5;
    g_wtp[gid] = (p < 4) ? src[co*576 + ci*9 + ky*3 + kx]
                         : src[co*576 + ci*9 + kx*3 + ky];
}

__global__ __launch_bounds__(256) void transpose_hw(
    const float* __restrict__ in, float* __restrict__ out)
{
    __shared__ float t[64][65];
    const size_t base = (size_t)blockIdx.x * 4096;
    const int c  = threadIdx.x & 63;
    const int r4 = threadIdx.x >> 6;
#pragma unroll
    for (int r = 0; r < 16; ++r) {
        int a = r4 * 16 + r;
        t[a][c] = in[base + a * 64 + c];
    }
    __syncthreads();
#pragma unroll
    for (int r = 0; r < 16; ++r) {
        int bb = r4 * 16 + r;
        out[base + (size_t)bb * 64 + c] = t[c][bb];
    }
}

// Persistent per-pass scan (r7-proven structure). 256 blocks x 512 threads;
// block = 4x4 px tile x 64 ch; 8 waves x 8-ci chunk (lane = co, weights in
// VGPRs). Sync: wave0 polls all 8 neighbor flags -> B0 -> exch reads (latency
// hidden under PhaseA) -> B1 -> PhaseB -> B2 reduce -> publish -> B3 -> flag.
//
// Register model (8 configs measured): 2nd launch_bounds arg = min waves/EU
// -> VGPR budget 512/waves. This body compiles to ~120 under (512,2). At 256
// blocks residency is 1 block/CU for ANY reg count -> no deadlock risk.
// 512-block topologies need a <=128-reg body; this compiler collapses to a
// 64-reg spill-fest when the body misses the budget (r8/r12-r14) or silently
// breaks co-residency when the budget allows >128 (r11). Stay at 256 blocks.
__global__ __launch_bounds__(512, 2) void pass_kernel(
    float* __restrict__ buf, const float* __restrict__ wtp,
    unsigned* __restrict__ flags, float* __restrict__ exch,
    int st, int su, int dir)
{
    __shared__ float lds[21504];   // 84 KB -> exactly 1 block/CU (all resident)
    float* rint = lds;             // [4 row][64 ci][4 col] own tile y[prev]
    float* ring = lds + 1024;      // [64 ci][28] halo cells (stride 28: 8-way
                                   // write conflicts vs 16-way at 24; reads
                                   // stay 16B-aligned since 112*ci % 16 == 0)
    float* red  = lds + 2816;      // [8 wv][16 px][64 lane] partials

    const int tid  = threadIdx.x;
    const int lane = tid & 63;
    const int wv   = tid >> 6;     // 0..7
    // XCD swizzle (bijective relabel; u-row neighbors share an XCD)
    const int B  = blockIdx.x;
    const int bu = ((B & 7) << 1) | ((B >> 7) & 1);
    const int bv = (B >> 3) & 15;
    const int b  = bu * 16 + bv;
    const int u0 = bu << 2, v0 = bv << 2;
    const int rr = wv >> 1, cc0 = (wv & 1) << 1;   // this wave's output px pair
    const int p0 = wv << 1;

    // per-lane weights for this wave's 8 ci
    float W[8][3][3];
#pragma unroll
    for (int i = 0; i < 8; ++i)
#pragma unroll
        for (int ky = 0; ky < 3; ++ky)
#pragma unroll
            for (int kx = 0; kx < 3; ++kx)
                W[i][ky][kx] = wtp[(((wv*8 + i)*3 + ky)*3 + kx)*64 + lane];

    // wave 0, lanes 0..7: one spatial neighbor flag each
    int nbr = -1;
    if (lane < 8) {
        int c  = lane + (lane >= 4 ? 1 : 0);
        int nu = bu + c/3 - 1, nv = bv + c%3 - 1;
        if (nu >= 0 && nu < 16 && nv >= 0 && nv < 16) nbr = (nu*16 + nv)*16;
    }

    // staging tables: this wave's ring cells (k = wv, wv+8, wv+16)
    int kk0=-1, kk1=-1, kk2=-1, so0=0, so1=0, so2=0;
#pragma unroll
    for (int j = 0; j < 3; ++j) {
        int k = wv + 8*j;
        if (k >= 20) continue;
        int row, col; kmap(k, row, col);
        int du = (row==0)?-1:(row==5)?1:0, dv = (col==0)?-1:(col==5)?1:0;
        int nu = bu + du, nv = bv + dv;
        if (nu < 0 || nu > 15 || nv < 0 || nv > 15) continue;
        int nb = nu*16 + nv;
        int lr = (row==0)?3:(row==5)?0:row-1;
        int lc = (col==0)?3:(col==5)?0:col-1;
        int so = (nb*16 + lr*4 + lc)*64 + lane;
        if      (j == 0) { kk0 = k; so0 = so; }
        else if (j == 1) { kk1 = k; so1 = so; }
        else             { kk2 = k; so2 = so; }
    }

    // prologue: y[t0] own tile + ring from buf (plain, fresh at dispatch)
    const int t0 = (dir > 0) ? 0 : 63;
    {
        const float2 iv = *(const float2*)(buf + (size_t)t0*st
              + (size_t)lane*CI_STRIDE + (size_t)(u0+rr)*su + (v0+cc0));
        *(float2*)&rint[(rr*64 + lane)*4 + cc0] = iv;
    }
#pragma unroll
    for (int j = 0; j < 3; ++j) {
        int k = wv + 8*j;
        if (k >= 20) continue;
        int row, col; kmap(k, row, col);
        int gu = u0 - 1 + row, gv = v0 - 1 + col;
        float v = 0.f;
        if (gu >= 0 && gu < 64 && gv >= 0 && gv < 64)
            v = buf[(size_t)t0*st + (size_t)lane*CI_STRIDE + (size_t)gu*su + gv];
        ring[lane*28 + k] = v;
    }
    __syncthreads();

    for (int s = 1; s <= 63; ++s) {
        const int t = (dir > 0) ? s : 63 - s;

        // wave 0 polls all 8 neighbor flags for step s-1 (throttled)
        if (wv == 0 && s > 1) {
            const unsigned tgt = (unsigned)(s - 1);
            bool ok = (nbr < 0);
            if (!ok) ok = __hip_atomic_load(&flags[nbr], __ATOMIC_RELAXED,
                                            __HIP_MEMORY_SCOPE_AGENT) >= tgt;
            int spins = 0;
            while (!__all(ok) && spins < (1 << 20)) {
                __builtin_amdgcn_s_sleep(1);
                if (!ok) ok = __hip_atomic_load(&flags[nbr], __ATOMIC_RELAXED,
                                                __HIP_MEMORY_SCOPE_AGENT) >= tgt;
                ++spins;
            }
        }
        __syncthreads();   // B0: all neighbor halos for step s-1 published

        // x[t] prefetch (plain cached; nobody else writes my px of slice t)
        const float2 xv = *(const float2*)(buf + (size_t)t*st
              + (size_t)lane*CI_STRIDE + (size_t)(u0+rr)*su + (v0+cc0));

        // issue exchange loads now (latency overlaps PhaseA below)
        float c0 = 0.f, c1 = 0.f, c2 = 0.f;
        if (s > 1) {
            const float* xsrc = exch + (size_t)((s-1) & 1) * EX_PAR;
            if (kk0 >= 0) c0 = ald(xsrc + so0);
            if (kk1 >= 0) c1 = ald(xsrc + so1);
            if (kk2 >= 0) c2 = ald(xsrc + so2);
        }

        float acc[16];
#pragma unroll
        for (int p = 0; p < 16; ++p) acc[p] = 0.f;

        // PHASE A: taps whose window cell is in the own tile (100/144)
#pragma unroll
        for (int i = 0; i < 8; ++i) {
            const int ci = wv*8 + i;
            const float4 R0 = *(const float4*)&rint[(0*64 + ci)*4];
            const float4 R1 = *(const float4*)&rint[(1*64 + ci)*4];
            const float4 R2 = *(const float4*)&rint[(2*64 + ci)*4];
            const float4 R3 = *(const float4*)&rint[(3*64 + ci)*4];
#pragma unroll
            for (int oi = 0; oi < 4; ++oi)
#pragma unroll
            for (int ky = 0; ky < 3; ++ky) {
                const int wr = oi + ky;
                if (wr < 1 || wr > 4) continue;
                const float4 Rw = (wr==1)?R0:(wr==2)?R1:(wr==3)?R2:R3;
#pragma unroll
                for (int oj = 0; oj < 4; ++oj)
#pragma unroll
                for (int kx = 0; kx < 3; ++kx) {
                    const int wc = oj + kx;
                    if (wc < 1 || wc > 4) continue;
                    acc[oi*4+oj] = fmaf(W[i][ky][kx], g4(Rw, wc-1), acc[oi*4+oj]);
                }
            }
        }

        // land the staged ring cells in LDS (loads drained under PhaseA)
        if (s > 1) {
            if (kk0 >= 0) ring[lane*28 + kk0] = c0;
            if (kk1 >= 0) ring[lane*28 + kk1] = c1;
            if (kk2 >= 0) ring[lane*28 + kk2] = c2;
        }
        __syncthreads();   // B1: ring complete

        // PHASE B: ring taps (44/144)
#pragma unroll
        for (int i = 0; i < 8; ++i) {
            const int ci = wv*8 + i;
            const float4 r0a = *(const float4*)&ring[ci*28 + 0];
            const float4 r5a = *(const float4*)&ring[ci*28 + 4];
            const float4 cl  = *(const float4*)&ring[ci*28 + 8];
            const float4 cr  = *(const float4*)&ring[ci*28 + 12];
            const float2 r0b = *(const float2*)&ring[ci*28 + 16];
            const float2 r5b = *(const float2*)&ring[ci*28 + 18];
#pragma unroll
            for (int oi = 0; oi < 4; ++oi)
#pragma unroll
            for (int ky = 0; ky < 3; ++ky) {
                const int wr = oi + ky;
#pragma unroll
                for (int oj = 0; oj < 4; ++oj)
#pragma unroll
                for (int kx = 0; kx < 3; ++kx) {
                    const int wc = oj + kx;
                    if (wr >= 1 && wr <= 4 && wc >= 1 && wc <= 4) continue;
                    float cell;
                    if      (wr == 0) cell = (wc < 4) ? g4(r0a, wc)
                                             : (wc == 4 ? r0b.x : r0b.y);
                    else if (wr == 5) cell = (wc < 4) ? g4(r5a, wc)
                                             : (wc == 4 ? r5b.x : r5b.y);
                    else if (wc == 0) cell = g4(cl, wr-1);
                    else              cell = g4(cr, wr-1);
                    acc[oi*4+oj] = fmaf(W[i][ky][kx], cell, acc[oi*4+oj]);
                }
            }
        }

        // partials -> LDS
#pragma unroll
        for (int p = 0; p < 16; ++p)
            red[(wv*16 + p)*64 + lane] = acc[p];
        __syncthreads();   // B2

        float s0 = 0.f, s1 = 0.f;
#pragma unroll
        for (int g2 = 0; g2 < 8; ++g2) {
            s0 += red[(g2*16 + p0    )*64 + lane];
            s1 += red[(g2*16 + p0 + 1)*64 + lane];
        }
        const float o0 = xv.x + fmaxf(s0, 0.f);
        const float o1 = xv.y + fmaxf(s1, 0.f);

        // output to buf (plain; read only after kernel boundary)
        *(float2*)(buf + (size_t)t*st + (size_t)lane*CI_STRIDE
                   + (size_t)(u0+rr)*su + (v0+cc0)) = make_float2(o0, o1);
        if (s < 63) {
            // next step's own tile (LDS) + coherent border publish
            *(float2*)&rint[(rr*64 + lane)*4 + cc0] = make_float2(o0, o1);
            float* eb = exch + (size_t)(s & 1)*EX_PAR + b*1024;
            ast(eb + (p0    )*64 + lane, o0);
            ast(eb + (p0 + 1)*64 + lane, o1);
        }
        __syncthreads();   // B3: drains all waves' stores before flag publish

        if (s < 63 && tid == 0)
            __hip_atomic_store(&flags[b*16], (unsigned)s, __ATOMIC_RELAXED,
                               __HIP_MEMORY_SCOPE_AGENT);
    }
}

extern "C" void kernel_launch(void* const* d_in, const int* in_sizes, int n_in,
                              void* d_out, int out_size, void* d_ws, size_t ws_size,
                              hipStream_t stream)
{
    (void)in_sizes; (void)n_in; (void)out_size; (void)d_ws; (void)ws_size;
    const float* x = (const float*)d_in[0];
    float* out = (float*)d_out;

    void *pa, *pb, *pw, *pf, *pe;
    hipGetSymbolAddress(&pa, HIP_SYMBOL(g_bufA));
    hipGetSymbolAddress(&pb, HIP_SYMBOL(g_bufB));
    hipGetSymbolAddress(&pw, HIP_SYMBOL(g_wtp));
    hipGetSymbolAddress(&pf, HIP_SYMBOL(g_flags));
    hipGetSymbolAddress(&pe, HIP_SYMBOL(g_exch));
    float* A  = (float*)pa + 16;
    float* Bb = (float*)pb + 16;
    float* wtp = (float*)pw;
    unsigned* flags = (unsigned*)pf;
    float* exch = (float*)pe;

    prep<<<864, 256, 0, stream>>>(
        (const float*)d_in[1], (const float*)d_in[2], (const float*)d_in[3],
        (const float*)d_in[4], (const float*)d_in[5], (const float*)d_in[6]);

    hipMemcpyAsync(A, x, (size_t)NELEM * sizeof(float),
                   hipMemcpyDeviceToDevice, stream);

    // layout0 [k][d][h][w]: UD/DU: t=h (st 64), u=d (su 4096), v=w
    pass_kernel<<<256, 512, 0, stream>>>(A, wtp + 0*WTP_PASS, flags + 0*4096, exch, 64, 4096, +1);
    pass_kernel<<<256, 512, 0, stream>>>(A, wtp + 1*WTP_PASS, flags + 1*4096, exch, 64, 4096, -1);

    transpose_hw<<<4096, 256, 0, stream>>>(A, Bb);   // -> layout1 [k][d][w][h]

    // LR/RL: t=w (st 64), u=d (su 4096), v=h
    pass_kernel<<<256, 512, 0, stream>>>(Bb, wtp + 2*WTP_PASS, flags + 2*4096, exch, 64, 4096, +1);
    pass_kernel<<<256, 512, 0, stream>>>(Bb, wtp + 3*WTP_PASS, flags + 3*4096, exch, 64, 4096, -1);
    // FB/BF: t=d (st 4096), u=w (su 64), v=h; weights spatially transposed
    pass_kernel<<<256, 512, 0, stream>>>(Bb, wtp + 4*WTP_PASS, flags + 4*4096, exch, 4096, 64, +1);
    pass_kernel<<<256, 512, 0, stream>>>(Bb, wtp + 5*WTP_PASS, flags + 5*4096, exch, 4096, 64, -1);

    transpose_hw<<<4096, 256, 0, stream>>>(Bb, out);
}